// Round 10
// baseline (39.529 us; speedup 1.0000x reference)
//
#include <hip/hip_runtime.h>

#define CC 512
#define CK 256
#define BB 8
#define TT 1024
#define POSTRIDE (CC * CC)

__device__ __forceinline__ float wave_allreduce(float v) {
#pragma unroll
    for (int m = 1; m < 64; m <<= 1) v += __shfl_xor(v, m, 64);
    return v;
}
__device__ __forceinline__ float dot4(float4 a, float4 b) {
    return a.x * b.x + a.y * b.y + a.z * b.z + a.w * b.w;
}

// D1: blocks [0,64):    fused chain  v1[b,:] (LDS) -> v2[b, c-seg]   (b=blk>>3)
//     blocks [64,320):  POpart[kc] = P[:, kc*128:+128] @ O[kc*128:+128, :]
//     blocks [320,448): t2[c] = P[c,:]@out_b + proj_b[c]   (1 row/wave)
__global__ void __launch_bounds__(256)
d1_kernel(const float* __restrict__ P, const float* __restrict__ O,
          const float* __restrict__ Wv, const float* __restrict__ bv,
          const float* __restrict__ W2, const float* __restrict__ b2,
          const float* __restrict__ ob, const float* __restrict__ pb,
          const float* __restrict__ cond,
          float* __restrict__ POpart, float* __restrict__ v2g,
          float* __restrict__ t2)
{
    const int blk = blockIdx.x, tid = threadIdx.x;
    const int lane = tid & 63, wvid = tid >> 6;

    if (blk < 64) {
        // ---- fused v1 -> v2 for batch b, columns [c0, c0+64)
        __shared__ float v1s[CC];
        const int b = blk >> 3, c0 = (blk & 7) * 64;
        const float4 cd = *(const float4*)&cond[b * CK + lane * 4];
        // phase 1: v1[b,:] — wave wvid owns rows [wvid*128, +128), 4 in flight
        for (int r = 0; r < 128; r += 4) {
            const int row = wvid * 128 + r;
            float s0 = dot4(*(const float4*)&Wv[(size_t)(row + 0) * CK + lane * 4], cd);
            float s1 = dot4(*(const float4*)&Wv[(size_t)(row + 1) * CK + lane * 4], cd);
            float s2 = dot4(*(const float4*)&Wv[(size_t)(row + 2) * CK + lane * 4], cd);
            float s3 = dot4(*(const float4*)&Wv[(size_t)(row + 3) * CK + lane * 4], cd);
            s0 = wave_allreduce(s0); s1 = wave_allreduce(s1);
            s2 = wave_allreduce(s2); s3 = wave_allreduce(s3);
            if (lane == 0) {
                v1s[row + 0] = s0 + bv[row + 0];
                v1s[row + 1] = s1 + bv[row + 1];
                v1s[row + 2] = s2 + bv[row + 2];
                v1s[row + 3] = s3 + bv[row + 3];
            }
        }
        __syncthreads();
        // phase 2: v2[b, c0..c0+64) — wave wvid owns 16 c's, 4 in flight
        const float4 va = *(const float4*)&v1s[lane * 4];
        const float4 vb = *(const float4*)&v1s[CK + lane * 4];
        for (int r = 0; r < 16; r += 4) {
            const int c = c0 + wvid * 16 + r;
            float s[4];
#pragma unroll
            for (int i = 0; i < 4; ++i) {
                const float4 wa = *(const float4*)&W2[(size_t)(c + i) * CC + lane * 4];
                const float4 wb = *(const float4*)&W2[(size_t)(c + i) * CC + CK + lane * 4];
                s[i] = dot4(wa, va) + dot4(wb, vb);
            }
#pragma unroll
            for (int i = 0; i < 4; ++i) s[i] = wave_allreduce(s[i]);
            if (lane == 0) {
#pragma unroll
                for (int i = 0; i < 4; ++i) v2g[b * CC + c + i] = s[i] + b2[c + i];
            }
        }
    } else if (blk < 320) {
        // ---- PO split-K GEMM (round-9 structure, 2-deep register prefetch)
        __shared__ float As[64][36];
        __shared__ float Bs[32][68];
        const int g = blk - 64;
        const int kc = g >> 6, t = g & 63;
        const int ti = t >> 3, tj = t & 7;
        const int ty = tid >> 4, tx = tid & 15;
        const int ar = tid >> 3, ac4 = (tid & 7) * 4;
        const int br = tid >> 4, bc4 = (tid & 15) * 4;
        float acc[4][4] = {};

        int kb = kc * 128;
        float4 a0 = *(const float4*)&P[(size_t)(ti * 64 + ar) * CC + kb + ac4];
        float4 a1 = *(const float4*)&P[(size_t)(ti * 64 + 32 + ar) * CC + kb + ac4];
        float4 b0 = *(const float4*)&O[(size_t)(kb + br) * CC + tj * 64 + bc4];
        float4 b1 = *(const float4*)&O[(size_t)(kb + 16 + br) * CC + tj * 64 + bc4];

        for (int ch = 0; ch < 4; ++ch) {
            __syncthreads();
            *(float4*)&As[ar][ac4] = a0;
            *(float4*)&As[32 + ar][ac4] = a1;
            *(float4*)&Bs[br][bc4] = b0;
            *(float4*)&Bs[16 + br][bc4] = b1;
            __syncthreads();
            if (ch < 3) {
                kb = kc * 128 + (ch + 1) * 32;
                a0 = *(const float4*)&P[(size_t)(ti * 64 + ar) * CC + kb + ac4];
                a1 = *(const float4*)&P[(size_t)(ti * 64 + 32 + ar) * CC + kb + ac4];
                b0 = *(const float4*)&O[(size_t)(kb + br) * CC + tj * 64 + bc4];
                b1 = *(const float4*)&O[(size_t)(kb + 16 + br) * CC + tj * 64 + bc4];
            }
#pragma unroll
            for (int kk = 0; kk < 32; ++kk) {
                const float a_0 = As[4 * ty + 0][kk];
                const float a_1 = As[4 * ty + 1][kk];
                const float a_2 = As[4 * ty + 2][kk];
                const float a_3 = As[4 * ty + 3][kk];
                const float4 bq = *(const float4*)&Bs[kk][4 * tx];
                acc[0][0] += a_0 * bq.x; acc[0][1] += a_0 * bq.y;
                acc[0][2] += a_0 * bq.z; acc[0][3] += a_0 * bq.w;
                acc[1][0] += a_1 * bq.x; acc[1][1] += a_1 * bq.y;
                acc[1][2] += a_1 * bq.z; acc[1][3] += a_1 * bq.w;
                acc[2][0] += a_2 * bq.x; acc[2][1] += a_2 * bq.y;
                acc[2][2] += a_2 * bq.z; acc[2][3] += a_2 * bq.w;
                acc[3][0] += a_3 * bq.x; acc[3][1] += a_3 * bq.y;
                acc[3][2] += a_3 * bq.z; acc[3][3] += a_3 * bq.w;
            }
        }
        float* dst = POpart + (size_t)kc * POSTRIDE +
                     (size_t)(ti * 64 + 4 * ty) * CC + tj * 64 + 4 * tx;
#pragma unroll
        for (int i = 0; i < 4; ++i) {
            float4 v = { acc[i][0], acc[i][1], acc[i][2], acc[i][3] };
            *(float4*)&dst[(size_t)i * CC] = v;
        }
    } else {
        // ---- t2: one row per wave (K=512)
        const int c = (blk - 320) * 4 + wvid;          // 0..511
        const float4 pa = *(const float4*)&P[(size_t)c * CC + lane * 4];
        const float4 pc = *(const float4*)&P[(size_t)c * CC + CK + lane * 4];
        const float4 oa = *(const float4*)&ob[lane * 4];
        const float4 oc = *(const float4*)&ob[CK + lane * 4];
        const float s = wave_allreduce(dot4(pa, oa) + dot4(pc, oc));
        if (lane == 0) t2[c] = s + pb[c];
    }
}

// D2: wave per (b,c) row: w = sum_p POpart[p][c,:]@v2[b,:] + t2[c];
//     out[b,c,:] = x[b,c,:] + w.
__global__ void __launch_bounds__(256)
stream_kernel(const float* __restrict__ x, const float* __restrict__ POpart,
              const float* __restrict__ t2, const float* __restrict__ v2,
              float* __restrict__ out)
{
    const int tid = threadIdx.x, lane = tid & 63;
    const int row = blockIdx.x * 4 + (tid >> 6);       // 0..4095
    const int b = row >> 9, c = row & 511;

    const float4* x4 = (const float4*)x + (size_t)row * (TT / 4);
    float4 xr[4];
#pragma unroll
    for (int i = 0; i < 4; ++i) xr[i] = x4[i * 64 + lane];

    const float4 ua = *(const float4*)&v2[b * CC + lane * 4];
    const float4 ub = *(const float4*)&v2[b * CC + CK + lane * 4];
    float acc = 0.f;
#pragma unroll
    for (int p = 0; p < 4; ++p) {
        const float* prow = POpart + (size_t)p * POSTRIDE + (size_t)c * CC;
        const float4 pa = *(const float4*)&prow[lane * 4];
        const float4 pc = *(const float4*)&prow[CK + lane * 4];
        acc += dot4(pa, ua) + dot4(pc, ub);
    }
    const float w = wave_allreduce(acc) + t2[c];

    float4* o4 = (float4*)out + (size_t)row * (TT / 4);
#pragma unroll
    for (int i = 0; i < 4; ++i) {
        float4 v = xr[i];
        v.x += w; v.y += w; v.z += w; v.w += w;
        o4[i * 64 + lane] = v;
    }
}

extern "C" void kernel_launch(void* const* d_in, const int* in_sizes, int n_in,
                              void* d_out, int out_size, void* d_ws, size_t ws_size,
                              hipStream_t stream) {
    const float* x    = (const float*)d_in[0];
    const float* cond = (const float*)d_in[1];
    const float* Wv   = (const float*)d_in[8];
    const float* bv   = (const float*)d_in[9];
    const float* W2   = (const float*)d_in[10] + 2 * CC * CC;  // in_proj_w rows [2C,3C)
    const float* b2   = (const float*)d_in[11] + 2 * CC;
    const float* O    = (const float*)d_in[12];
    const float* ob   = (const float*)d_in[13];
    const float* P    = (const float*)d_in[14];
    const float* pb   = (const float*)d_in[15];
    float* out = (float*)d_out;

    float* POpart = (float*)d_ws;                  // 4 x 1 MB partials
    float* v2 = POpart + 4 * POSTRIDE;             // 4096 f
    float* t2 = v2 + BB * CC;                      // 512 f

    d1_kernel<<<448, 256, 0, stream>>>(P, O, Wv, bv, W2, b2, ob, pb, cond,
                                       POpart, v2, t2);
    stream_kernel<<<1024, 256, 0, stream>>>(x, POpart, t2, v2, out);
}